// Round 7
// baseline (952.631 us; speedup 1.0000x reference)
//
#include <hip/hip_runtime.h>
#include <math.h>

// B=4, H=256, W=256, 100 iters. Closed-form mu-only update (sigma/rou are
// dead code for the mu output; r14 evidence):
//   dmu = 2*uw1*mu + uw2*y + ew0*dn + ew1*rt + ew0_up*up + ew1_lf*lf
// Round 15: PERSISTENT KERNEL. r6's 15us/launch decomposed as ~3 DS + ~3
// mem + ~8-9 unexplained -> launch gap/ramp. Replace 10 launches with ONE
// kernel: 10 phases, neighbor halo exchange via phase-indexed device-scope
// flags (release store after __threadfence; acquire poll). 256 blocks <=
// 256 CUs -> co-resident by capacity -> no deadlock. The flag wait (before
// phase-p loads) also orders neighbor phase-p+1 overwrites of plane[p&1]
// after my phase-p reads. Torus wrap (&255) == jnp.roll, exact.
// Persistence bonuses: k1/k2 coefficient regs loaded ONCE (was 45KB/block
// x10 launches); interior mu/v kept in regs across phases (only 1784 halo
// px of 2808 reload). Iteration core byte-identical to r6 (T=10, 54x52
// tile, TS=53, RPT=3, shrinking row gate, 1 barrier/iter).
#define NPIX   262144
#define T      10
#define NPHASE 10
#define TILE_R 54
#define TILE_C 52
#define TS     53            // padded LDS row stride (floats)
#define RPT    3
#define NRG    18            // 18*3 = 54 exact
#define ACTIVE (TILE_C*NRG)  // 936 active threads of 1024
#define NTHR   1024
#define HALO_R 11
#define HALO_C 10

__device__ __forceinline__ float clampf(float x, float lo, float hi) {
    return fminf(fmaxf(x, lo), hi);
}

// c1 = {2*uw1, uw2*y, ew0(down-edge), ew1(right-edge)}.
__global__ __launch_bounds__(NTHR) void persist_kernel(
    float* __restrict__ muA, float* __restrict__ muB,
    float* __restrict__ vA,  float* __restrict__ vB,
    const float4* __restrict__ c1,
    float* __restrict__ mu_out,
    unsigned int* __restrict__ flags)   // [NPHASE][256], pre-zeroed
{
    __shared__ float buf[2][TILE_R*TS];   // 22.9 KB

    int tid = threadIdx.x;
    int rg  = tid / TILE_C;
    int col = tid - rg*TILE_C;
    bool act = (tid < ACTIVE);
    int bx = blockIdx.x, by = blockIdx.y, bz = blockIdx.z;
    int h0 = by * 32, w0 = bx * 32;
    int w  = (w0 + col - HALO_C) & 255;
    int r0 = RPT*rg;
    int bid = (bz << 6) | (by << 3) | bx;

    // neighbor flag slot (8-neighborhood on the 8x8 torus of tiles)
    int nbSlot = 0;
    if (tid < 8) {
        const int dxs[8] = {-1, 0, 1,-1, 1,-1, 0, 1};
        const int dys[8] = {-1,-1,-1, 0, 0, 1, 1, 1};
        int nx = (bx + dxs[tid]) & 7;
        int ny = (by + dys[tid]) & 7;
        nbSlot = (bz << 6) | (ny << 3) | nx;
    }

    float mu[RPT], v[RPT];
    float4 k1[RPT];
    float k2x0 = 0.f, k2y[RPT];
    int  gg[RPT];
    bool keep[RPT];

    // ---- phase-invariant: coefficients + indices, loaded ONCE ----
    if (act) {
#pragma unroll
        for (int k = 0; k < RPT; ++k) {
            int r = r0 + k;
            int h = (h0 + r - HALO_R) & 255;
            gg[k] = (bz << 16) | (h << 8) | w;
            keep[k] = (r >= HALO_R && r < HALO_R+32 &&
                       col >= HALO_C && col < HALO_C+32);
            k1[k] = c1[gg[k]];
        }
        int hu = (h0 + ((r0 == 0) ? 0 : r0-1) - HALO_R) & 255;
        k2x0 = c1[(bz << 16) | (hu << 8) | w].z;
        int wl = (w0 + ((col == 0) ? 0 : col-1) - HALO_C) & 255;
#pragma unroll
        for (int k = 0; k < RPT; ++k) {
            int h = (gg[k] >> 8) & 255;
            k2y[k] = c1[(bz << 16) | (h << 8) | wl].w;
        }
    }

    int cl = (col == 0)        ? 0        : col-1;
    int cr = (col == TILE_C-1) ? TILE_C-1 : col+1;

    for (int p = 0; p < NPHASE; ++p) {
        const float* __restrict__ muSrc = (p & 1) ? muB : muA;
        const float* __restrict__ vSrc  = (p & 1) ? vB  : vA;
        float* __restrict__ muDst = (p & 1) ? muA : muB;
        float* __restrict__ vDst  = (p & 1) ? vA  : vB;

        // ---- wait for 8 neighbors' phase p-1 (protects loads AND our
        //      upcoming overwrites of the plane they read) ----
        if (p) {
            if (tid < 8) {
                const unsigned int* f = &flags[(p-1)*256 + nbSlot];
                while (__hip_atomic_load(f, __ATOMIC_ACQUIRE,
                                         __HIP_MEMORY_SCOPE_AGENT) == 0u)
                    __builtin_amdgcn_s_sleep(8);
            }
            __syncthreads();
        }

        // ---- stage LDS buf0; reload only halo regs (interior kept) ----
        if (act) {
#pragma unroll
            for (int k = 0; k < RPT; ++k) {
                if (p == 0)        { mu[k] = muSrc[gg[k]]; v[k] = 0.f; }
                else if (!keep[k]) { mu[k] = muSrc[gg[k]]; v[k] = vSrc[gg[k]]; }
                buf[0][(r0+k)*TS + col] = mu[k];
            }
        }
        __syncthreads();

        // ---- T fused Jacobi iterations (identical to r6 core) ----
        for (int s = 0; s < T; ++s) {
            const float* __restrict__ cur = buf[s & 1];
            float*       __restrict__ nxt = buf[(s & 1) ^ 1];
            int rgLo = (s + 2) / 3;      // useful rows [2+s, 51-s]
            int rgHi = (51 - s) / 3;
            if (act && rg >= rgLo && rg <= rgHi) {
                float nmu[RPT];
                float up0 = cur[((rg == 0)     ? 0          : (r0-1))*TS + col];
                float dnL = cur[((rg == NRG-1) ? (TILE_R-1) : (r0+RPT))*TS + col];
#pragma unroll
                for (int k = 0; k < RPT; ++k) {
                    int r = r0 + k;
                    float lf = cur[r*TS + cl];
                    float rt = cur[r*TS + cr];
                    float up = (k == 0)     ? up0 : mu[k-1];
                    float dn = (k == RPT-1) ? dnL : mu[k+1];
                    float4 K = k1[k];
                    float K2x = (k == 0) ? k2x0 : k1[k-1].z;
                    float dmu = K.x*mu[k] + K.y + K.z*dn + K.w*rt
                              + K2x*up + k2y[k]*lf;
                    v[k] = 0.7f*v[k] + 0.01f*dmu;
                    nmu[k] = clampf(mu[k] + v[k], 0.f, 63.f);
                }
#pragma unroll
                for (int k = 0; k < RPT; ++k) {
                    mu[k] = nmu[k];
                    nxt[(r0 + k)*TS + col] = nmu[k];
                }
            }
            __syncthreads();   // all reads of cur done AND nxt fully written
        }

        // ---- store interior; signal phase completion ----
        if (p == NPHASE-1) {
            if (act) {
#pragma unroll
                for (int k = 0; k < RPT; ++k)
                    if (keep[k]) mu_out[gg[k]] = mu[k];
            }
        } else {
            if (act) {
#pragma unroll
                for (int k = 0; k < RPT; ++k)
                    if (keep[k]) { muDst[gg[k]] = mu[k]; vDst[gg[k]] = v[k]; }
            }
            __threadfence();       // stores visible at agent scope
            __syncthreads();       // all threads' fences done before signal
            if (tid == 0)
                __hip_atomic_store(&flags[p*256 + bid], 1u,
                                   __ATOMIC_RELEASE, __HIP_MEMORY_SCOPE_AGENT);
        }
    }
}

// init mu plane + invariant coefficient plane
__global__ __launch_bounds__(256) void init_state_kernel(
    const float*  __restrict__ y,
    const float2* __restrict__ ew,
    const float2* __restrict__ uw,
    float* muA, float4* c1)
{
    int idx = blockIdx.x*256 + threadIdx.x;
    float2 e   = ew[idx];
    float2 uwv = uw[idx];
    float  yv  = y[idx];
    muA[idx] = yv;
    c1[idx]  = make_float4(2.f*uwv.x, uwv.y*yv, e.x, e.y);
}

extern "C" void kernel_launch(void* const* d_in, const int* in_sizes, int n_in,
                              void* d_out, int out_size, void* d_ws, size_t ws_size,
                              hipStream_t stream) {
    const float* y  = (const float*)d_in[0];
    const float* ew = (const float*)d_in[1];
    const float* uw = (const float*)d_in[2];
    float* out = (float*)d_out;
    const int N = NPIX;

    // workspace: c1 (float4 plane) + muA, muB, vA, vB (float planes)
    //            + flags[NPHASE][256]   (~8 MB total)
    float4* c1  = (float4*)d_ws;
    float*  muA = (float*)(c1 + N);
    float*  muB = muA + N;
    float*  vA  = muB + N;
    float*  vB  = vA + N;
    unsigned int* flags = (unsigned int*)(vB + N);

    hipMemsetAsync(flags, 0, NPHASE*256*sizeof(unsigned int), stream);
    hipLaunchKernelGGL(init_state_kernel, dim3(N/256), dim3(256), 0, stream,
                       y, (const float2*)ew, (const float2*)uw, muA, c1);
    hipLaunchKernelGGL(persist_kernel, dim3(8, 8, 4), dim3(NTHR), 0, stream,
                       muA, muB, vA, vB, c1, out, flags);
}

// Round 8
// 163.627 us; speedup vs baseline: 5.8220x; 5.8220x over previous
//
#include <hip/hip_runtime.h>
#include <math.h>

// B=4, H=256, W=256, 100 iters. Closed-form mu-only update (sigma/rou are
// dead code for the mu output):
//   dmu = 2*uw1*mu + uw2*y + ew0*dn + ew1*rt + ew0_up*up + ew1_lf*lf
// Round 16: revert r15's persistent kernel (VALUBusy 2.5% -> 97% idle in
// cross-XCD flag sync; kernel boundaries win). Base = r14 (151.7us).
// Row-major thread layout: each thread owns 1 row x 4 contiguous cols ->
// LDS per thread-iter becomes {up b128, dn b128, lf b32, rt b32, wr b128}
// = 5 instr / 4 px vs 11 b32 / 3 px. Exact per-row shrinking gate
// (rows [2+s, 51-s]) instead of rowgroup gate: avg active waves 11.1->8.3.
// DS cyc/CU-iter ~710 -> ~395 (-44%); r2/r5/r6 established wall time moves
// ~1:1 with DS-pipe cycles. TS=60 floats: rows 16B-aligned for b128;
// segment-class step 15 mod 8 = 7 (coprime) -> balanced banks. k2 coeffs
// staged via dedicated LDS planes (ewz/eww) -> no scattered global reads,
// no extra barrier (planes never overwritten). Validity: per-row gate is
// the exact need-set recurrence; reads at step s hit rows [1+s,52-s] =
// prior gate's writes; stored rows 11..42 = final gate [11,42] exactly.
// Temporal blocking: T=10 iters/launch, 54x52 tile (halo 11 rows/10 cols),
// 256 blocks (1/CU), double-buffered LDS, 1 barrier/iter.
#define NPIX   262144
#define T      10
#define TILE_R 54
#define TILE_C 52
#define TS     60            // padded LDS row stride (floats), mult of 4
#define NCG    13            // colgroups of 4: 13*4 = 52
#define ACTIVE (TILE_R*NCG)  // 702 active threads of 768
#define NTHR   768
#define HALO_R 11
#define HALO_C 10

__device__ __forceinline__ float clampf(float x, float lo, float hi) {
    return fminf(fmaxf(x, lo), hi);
}

// c1 = {2*uw1, uw2*y, ew0(down-edge), ew1(right-edge)}.
__global__ __launch_bounds__(NTHR) void tile_kernel(
    const float* __restrict__ muI, const float* __restrict__ vI,
    float* __restrict__ muO, float* __restrict__ vO,
    const float4* __restrict__ c1,
    float* __restrict__ mu_out,   // non-null on last launch (mu/v not stored)
    int first)                    // launch 0: v := 0, vI not read
{
    __shared__ float buf[2][TILE_R*TS];   // 25.9 KB
    __shared__ float ewz[TILE_R*TS];      // staged ew0 plane (12.9 KB)
    __shared__ float eww[TILE_R*TS];      // staged ew1 plane (12.9 KB)

    int tid = threadIdx.x;
    int r   = tid / NCG;          // 0..53: own row
    int cg  = tid - r*NCG;        // 0..12: own colgroup (cols 4cg..4cg+3)
    bool act = (tid < ACTIVE);
    int bz = blockIdx.z;
    int h0 = blockIdx.y * 32;
    int w0 = blockIdx.x * 32;
    int c0 = 4*cg;
    int h  = (h0 + r - HALO_R) & 255;

    float mu[4], v[4];
    float4 k1[4];
    float k2x[4], k2y = 0.f;
    int gi[4];

    // ---- load: mu/v/k1 per px; stage mu->buf0, ew0/ew1->planes ----
    if (act) {
#pragma unroll
        for (int j = 0; j < 4; ++j) {
            int wv = (w0 + c0 + j - HALO_C) & 255;
            gi[j] = (bz << 16) | (h << 8) | wv;
            mu[j] = muI[gi[j]];
            v[j]  = first ? 0.f : vI[gi[j]];
            float4 K = c1[gi[j]];
            k1[j] = K;
            buf[0][r*TS + c0 + j] = mu[j];
            ewz[r*TS + c0 + j] = K.z;
            eww[r*TS + c0 + j] = K.w;
        }
    }
    __syncthreads();

    // boundary neighbor coeffs from staged planes (clamped at tile edge ->
    // finite garbage; edge px are garbage-region by the validity argument)
    if (act) {
        int ru = (r == 0) ? 0 : r-1;
        float4 t = *(const float4*)&ewz[ru*TS + c0];
        k2x[0] = t.x; k2x[1] = t.y; k2x[2] = t.z; k2x[3] = t.w;
        k2y = eww[r*TS + ((cg == 0) ? 0 : c0-1)];
    }
    // no extra barrier needed: ewz/eww are never written again, and iter 0
    // writes buf[1] which nobody reads before the s=0 barrier.

    // ---- T fused Jacobi iterations, one barrier each, per-row gate ----
    for (int s = 0; s < T; ++s) {
        const float* __restrict__ cur = buf[s & 1];
        float*       __restrict__ nxt = buf[(s & 1) ^ 1];
        if (act && r >= 2+s && r <= 51-s) {     // exact need(s+1) rows
            float4 up4 = *(const float4*)&cur[(r-1)*TS + c0];  // r>=2
            float4 dn4 = *(const float4*)&cur[(r+1)*TS + c0];  // r<=51
            float lf = cur[r*TS + ((cg == 0)     ? 0  : c0-1)];
            float rt = cur[r*TS + ((cg == NCG-1) ? 51 : c0+4)];
            float up[4] = {up4.x, up4.y, up4.z, up4.w};
            float dn[4] = {dn4.x, dn4.y, dn4.z, dn4.w};
            float nmu[4];
#pragma unroll
            for (int j = 0; j < 4; ++j) {
                float L = (j == 0) ? lf : mu[j-1];
                float R = (j == 3) ? rt : mu[j+1];
                float4 K = k1[j];
                float K2x = k2x[j];
                float K2y = (j == 0) ? k2y : k1[j-1].w;
                float dmu = K.x*mu[j] + K.y + K.z*dn[j] + K.w*R
                          + K2x*up[j] + K2y*L;
                v[j] = 0.7f*v[j] + 0.01f*dmu;
                nmu[j] = clampf(mu[j] + v[j], 0.f, 63.f);
            }
            float4 o = make_float4(nmu[0], nmu[1], nmu[2], nmu[3]);
            *(float4*)&nxt[r*TS + c0] = o;
#pragma unroll
            for (int j = 0; j < 4; ++j) mu[j] = nmu[j];
        }
        __syncthreads();   // all reads of cur done AND nxt fully written
    }

    // ---- store interior (rows [HALO_R, +32), cols [HALO_C, +32)) ----
    if (act && r >= HALO_R && r < HALO_R+32) {
#pragma unroll
        for (int j = 0; j < 4; ++j) {
            int c = c0 + j;
            if (c >= HALO_C && c < HALO_C+32) {
                if (mu_out) {
                    mu_out[gi[j]] = mu[j];   // final launch: only mu needed
                } else {
                    muO[gi[j]] = mu[j];
                    vO[gi[j]]  = v[j];
                }
            }
        }
    }
}

// init mu plane + invariant coefficient plane
__global__ __launch_bounds__(256) void init_state_kernel(
    const float*  __restrict__ y,
    const float2* __restrict__ ew,
    const float2* __restrict__ uw,
    float* muA, float4* c1)
{
    int idx = blockIdx.x*256 + threadIdx.x;
    float2 e   = ew[idx];
    float2 uwv = uw[idx];
    float  yv  = y[idx];
    muA[idx] = yv;
    c1[idx]  = make_float4(2.f*uwv.x, uwv.y*yv, e.x, e.y);
}

extern "C" void kernel_launch(void* const* d_in, const int* in_sizes, int n_in,
                              void* d_out, int out_size, void* d_ws, size_t ws_size,
                              hipStream_t stream) {
    const float* y  = (const float*)d_in[0];
    const float* ew = (const float*)d_in[1];
    const float* uw = (const float*)d_in[2];
    float* out = (float*)d_out;
    const int N = NPIX;

    // workspace: c1 (float4 plane) + muA, muB, vA, vB (float planes) ~8 MB
    float4* c1  = (float4*)d_ws;
    float*  muA = (float*)(c1 + N);
    float*  muB = muA + N;
    float*  vA  = muB + N;
    float*  vB  = vA + N;

    hipLaunchKernelGGL(init_state_kernel, dim3(N/256), dim3(256), 0, stream,
                       y, (const float2*)ew, (const float2*)uw, muA, c1);

    float *muI = muA, *muO = muB, *vI = vA, *vO = vB;
    const int NLAUNCH = 100 / T;   // 10
    for (int l = 0; l < NLAUNCH; ++l) {
        float* mo = (l == NLAUNCH-1) ? out : nullptr;
        hipLaunchKernelGGL(tile_kernel, dim3(8, 8, 4), dim3(NTHR), 0, stream,
                           muI, vI, muO, vO, c1, mo, (l == 0) ? 1 : 0);
        float* t;
        t = muI; muI = muO; muO = t;
        t = vI;  vI  = vO;  vO  = t;
    }
}

// Round 9
// 141.066 us; speedup vs baseline: 6.7531x; 1.1599x over previous
//
#include <hip/hip_runtime.h>
#include <math.h>

// B=4, H=256, W=256, 100 iters. Closed-form mu-only update (sigma/rou are
// dead code for the mu output):
//   dmu = 2*uw1*mu + uw2*y + ew0*dn + ew1*rt + ew0_up*up + ew1_lf*lf
// Round 17: DPP lateral neighbors. Revert r16 (b128 restructure regressed;
// r6 col-major b32 layout is the right base). Tile = 64x64 (halo 16), so
// lane == tile col and each 64-lane wave == one 4-row strip. lf/rt now come
// from wave_shr1/wave_shl1 DPP (VALU pipe, 0x138/0x130 - gfx9 modes kept on
// CDNA) instead of LDS; LDS holds ONLY strip-boundary rows (r0, r0+3).
// Per wave-iter DS: {up b32, dn b32, 2x wr b32} = 4 vs r6's 11 (-64%).
// DPP lane-0/63 fallback (=0) lands only in tile cols 0/63; col validity
// envelope after t steps = [t, 63-t] which at t=15 still covers stored
// cols [16,47]. Row gate [17-Tl+s, 46+Tl-s] at strip granularity (over-
// compute outside the gate writes finite garbage only into never-needed
// rows - r2-style stale-front argument). 64-col geometry -> halo 16 ->
// T=15: 7 launches (6x15 + 1x10) vs 10. 1024 threads exact, no masking.
#define NPIX  262144
#define TILE  64
#define TS    65             // padded LDS row stride (floats)
#define RPT   4
#define NSTRIP 16            // 16 strips x 4 rows = 64
#define NTHR  1024
#define HALO  16

__device__ __forceinline__ float clampf(float x, float lo, float hi) {
    return fminf(fmaxf(x, lo), hi);
}
// wave-wide lateral shifts on the VALU pipe (gfx9 DPP, valid on CDNA)
__device__ __forceinline__ float dpp_shr1(float x) {   // lane l <- lane l-1
    int i = __builtin_amdgcn_update_dpp(0, __float_as_int(x),
                                        0x138, 0xf, 0xf, false);
    return __int_as_float(i);
}
__device__ __forceinline__ float dpp_shl1(float x) {   // lane l <- lane l+1
    int i = __builtin_amdgcn_update_dpp(0, __float_as_int(x),
                                        0x130, 0xf, 0xf, false);
    return __int_as_float(i);
}

// c1 = {2*uw1, uw2*y, ew0(down-edge), ew1(right-edge)}.
__global__ __launch_bounds__(NTHR) void tile_kernel(
    const float* __restrict__ muI, const float* __restrict__ vI,
    float* __restrict__ muO, float* __restrict__ vO,
    const float4* __restrict__ c1,
    float* __restrict__ mu_out,   // non-null on last launch (mu/v not stored)
    int Tl,                       // iterations this launch (15 or 10)
    int first)                    // launch 0: v := 0, vI not read
{
    __shared__ float buf[2][TILE*TS];   // 33.3 KB

    int tid  = threadIdx.x;
    int rg   = tid >> 6;          // wave index == strip index (rows 4rg..+3)
    int lane = tid & 63;          // == tile col
    int bz = blockIdx.z;
    int h0 = blockIdx.y * 32;
    int w0 = blockIdx.x * 32;
    int w  = (w0 + lane - HALO) & 255;
    int r0 = RPT*rg;

    float mu[RPT], v[RPT];
    float4 k1[RPT];
    float k2y[RPT];      // ew1 of left-col neighbor (via DPP on k1.w)
    float k2x0;          // ew0 of up-row neighbor for k=0 (global read)
    int gi[RPT];

    // ---- load: fully coalesced per row (64 consecutive cols) ----
#pragma unroll
    for (int k = 0; k < RPT; ++k) {
        int h = (h0 + r0 + k - HALO) & 255;
        gi[k] = (bz << 16) | (h << 8) | w;
        mu[k] = muI[gi[k]];
        v[k]  = first ? 0.f : vI[gi[k]];
        k1[k] = c1[gi[k]];
        k2y[k] = dpp_shr1(k1[k].w);   // left neighbor's ew1 (lane0: 0, garbage col)
    }
    {
        int hu = (h0 + ((rg == 0) ? 0 : r0-1) - HALO) & 255;
        k2x0 = c1[(bz << 16) | (hu << 8) | w].z;   // up-nb ew0 for row k=0
    }
    // stage only strip-boundary rows (the only LDS-read rows)
    buf[0][r0*TS + lane]       = mu[0];
    buf[0][(r0 + 3)*TS + lane] = mu[3];
    __syncthreads();

    // ---- Tl fused Jacobi iterations, one barrier each, strip row gate ----
    for (int s = 0; s < Tl; ++s) {
        const float* __restrict__ cur = buf[s & 1];
        float*       __restrict__ nxt = buf[(s & 1) ^ 1];
        // useful rows [17-Tl+s, 46+Tl-s]; strip granular
        int lo = 14 - Tl + s;                    // 4rg >= lo
        int rgLo = (lo <= 0) ? 0 : ((lo + 3) >> 2);
        int rgHi = (46 + Tl - s) >> 2;           // <= 15 always for Tl<=15
        if (rg >= rgLo && rg <= rgHi) {          // wave-uniform branch
            float up0 = cur[((rg == 0)        ? 0        : (r0-1))*TS + lane];
            float dnL = cur[((rg == NSTRIP-1) ? (TILE-1) : (r0+RPT))*TS + lane];
            float nmu[RPT];
#pragma unroll
            for (int k = 0; k < RPT; ++k) {
                float up = (k == 0)     ? up0 : mu[k-1];
                float dn = (k == RPT-1) ? dnL : mu[k+1];
                float lf = dpp_shr1(mu[k]);      // VALU pipe, no LDS
                float rt = dpp_shl1(mu[k]);
                float4 K = k1[k];
                float K2x = (k == 0) ? k2x0 : k1[k-1].z;
                float dmu = K.x*mu[k] + K.y + K.z*dn + K.w*rt
                          + K2x*up + k2y[k]*lf;
                v[k] = 0.7f*v[k] + 0.01f*dmu;
                nmu[k] = clampf(mu[k] + v[k], 0.f, 63.f);
            }
#pragma unroll
            for (int k = 0; k < RPT; ++k) mu[k] = nmu[k];
            nxt[r0*TS + lane]       = mu[0];
            nxt[(r0 + 3)*TS + lane] = mu[3];
        }
        __syncthreads();   // all reads of cur done AND nxt boundary rows written
    }

    // ---- store interior (rows [16,48), cols [16,48)) ----
    if (lane >= HALO && lane < HALO+32) {
#pragma unroll
        for (int k = 0; k < RPT; ++k) {
            int r = r0 + k;
            if (r >= HALO && r < HALO+32) {
                if (mu_out) {
                    mu_out[gi[k]] = mu[k];   // final launch: only mu needed
                } else {
                    muO[gi[k]] = mu[k];
                    vO[gi[k]]  = v[k];
                }
            }
        }
    }
}

// init mu plane + invariant coefficient plane
__global__ __launch_bounds__(256) void init_state_kernel(
    const float*  __restrict__ y,
    const float2* __restrict__ ew,
    const float2* __restrict__ uw,
    float* muA, float4* c1)
{
    int idx = blockIdx.x*256 + threadIdx.x;
    float2 e   = ew[idx];
    float2 uwv = uw[idx];
    float  yv  = y[idx];
    muA[idx] = yv;
    c1[idx]  = make_float4(2.f*uwv.x, uwv.y*yv, e.x, e.y);
}

extern "C" void kernel_launch(void* const* d_in, const int* in_sizes, int n_in,
                              void* d_out, int out_size, void* d_ws, size_t ws_size,
                              hipStream_t stream) {
    const float* y  = (const float*)d_in[0];
    const float* ew = (const float*)d_in[1];
    const float* uw = (const float*)d_in[2];
    float* out = (float*)d_out;
    const int N = NPIX;

    // workspace: c1 (float4 plane) + muA, muB, vA, vB (float planes) ~8 MB
    float4* c1  = (float4*)d_ws;
    float*  muA = (float*)(c1 + N);
    float*  muB = muA + N;
    float*  vA  = muB + N;
    float*  vB  = vA + N;

    hipLaunchKernelGGL(init_state_kernel, dim3(N/256), dim3(256), 0, stream,
                       y, (const float2*)ew, (const float2*)uw, muA, c1);

    // 6 launches of 15 iters + final launch of 10 = 100
    static const int Tls[7] = {15, 15, 15, 15, 15, 15, 10};
    float *muI = muA, *muO = muB, *vI = vA, *vO = vB;
    for (int l = 0; l < 7; ++l) {
        float* mo = (l == 6) ? out : nullptr;
        hipLaunchKernelGGL(tile_kernel, dim3(8, 8, 4), dim3(NTHR), 0, stream,
                           muI, vI, muO, vO, c1, mo, Tls[l], (l == 0) ? 1 : 0);
        float* t;
        t = muI; muI = muO; muO = t;
        t = vI;  vI  = vO;  vO  = t;
    }
}